// Round 1
// baseline (446.289 us; speedup 1.0000x reference)
//
#include <hip/hip_runtime.h>

// EGNN fused layer, MI355X gfx950 — v2 (VALU-cut round).
// out[0 : 50000*64)          = h + segment_sum(node messages, dst)
// out[50000*64 : +50000*3)   = x + segment_sum(coord updates, dst)
//
// Changes vs v1 (415 us, VALUBusy 57% / MfmaUtil 10% -> VALU-issue bound):
//  - edge-MLP second layer folded into GEMM1: prep kernel computes
//    Wn1' = [Wn1[0:128]; We2@Wn1[128:160]], bn1' = bn1 + be2@Wn1[128:160]
//    (same for coord path) into d_ws; kernel stages s = silu(d*We1+be1)
//    directly as the last 32 m_input columns.  (-256 FMA/thread/tile)
//  - silu via __fdividef + __expf (4 ops vs ~12 for IEEE div path)
//  - f2bf via HW cvt ((__bf16) cast) instead of 3-op software RNE
//  - coord path: in-register butterfly reduce of GEMM1 C-frags
//    (no second hl round trip, no matvec, one fewer __syncthreads)
//  - LDS 46.1 -> 40.7 KB (dist_l/we2_l/be2_l/wc2_l dropped)

#define NN 50000
#define NE 800000
#define NDIM 64
#define HDIM 128
#define EDIM 32
#define NTILES (NE / 64)      // 12500, exact
#define MSTRIDE 168           // m_input LDS row stride (ushorts): 160 + 8 pad
#define HSTRIDE 136           // hidden LDS row stride: 128 + 8 pad
#define NH (NN * NDIM)        // 3,200,000
#define NX (NN * 3)           // 150,000

// workspace layout (floats)
#define WS_WN1P 0             // [160][128]
#define WS_WC1P 20480         // [160][128]
#define WS_BN1P 40960         // [128]
#define WS_BC1P 41088         // [128]

typedef __bf16 bf16x8 __attribute__((ext_vector_type(8)));
typedef float f32x4 __attribute__((ext_vector_type(4)));
typedef unsigned short ushort8 __attribute__((ext_vector_type(8)));
typedef unsigned short ushort4v __attribute__((ext_vector_type(4)));

__device__ __forceinline__ unsigned short f2bf(float f) {
    union { __bf16 b; unsigned short u; } c;
    c.b = (__bf16)f;            // HW v_cvt (RNE), 1 op — m240: compiler handles this well
    return c.u;
}
__device__ __forceinline__ float silu(float v) {
    return __fdividef(v, 1.0f + __expf(-v));   // fast rcp path, ~4 ops
}

__device__ __forceinline__ bf16x8 ld_frag(const unsigned short* p) {
    union { ushort8 u; bf16x8 v; } c;
    c.u = *(const ushort8*)p;
    return c.v;
}
__device__ __forceinline__ bf16x8 mk_frag(const unsigned short* u) {
    union { ushort8 uu; bf16x8 v; } c;
#pragma unroll
    for (int j = 0; j < 8; ++j) c.uu[j] = u[j];
    return c.v;
}

__global__ void init_out(const float* __restrict__ h, const float* __restrict__ x,
                         float* __restrict__ out) {
    int i = blockIdx.x * 256 + threadIdx.x;
    if (i < NH) out[i] = h[i];
    else if (i < NH + NX) out[i] = x[i - NH];
}

// Fold We2/be2 into the 160->128 GEMM weights.  Grid: 322 blocks x 128 thr.
//  b in [0,160):   Wn1p row b      b in [160,320): Wc1p row b-160
//  b==320: bn1p    b==321: bc1p
__global__ __launch_bounds__(128) void fold_weights(
    const float* __restrict__ We2, const float* __restrict__ be2,
    const float* __restrict__ Wn1, const float* __restrict__ bn1,
    const float* __restrict__ Wc1, const float* __restrict__ bc1,
    float* __restrict__ ws) {
    const int b = blockIdx.x;
    const int col = threadIdx.x;
    if (b < 320) {
        const int path = (b >= 160);
        const float* W = path ? Wc1 : Wn1;
        float* Wp = ws + (path ? WS_WC1P : WS_WN1P);
        const int r = path ? (b - 160) : b;
        if (r < 128) {
            Wp[r * 128 + col] = W[r * 128 + col];
        } else {
            const int j = r - 128;          // s-dim index 0..31
            float s = 0.0f;
#pragma unroll
            for (int n = 0; n < 32; ++n)
                s += We2[j * 32 + n] * W[(128 + n) * 128 + col];
            Wp[r * 128 + col] = s;
        }
    } else {
        const int path = b - 320;
        const float* W = path ? Wc1 : Wn1;
        const float* bb = path ? bc1 : bn1;
        float* bp = ws + (path ? WS_BC1P : WS_BN1P);
        float s = bb[col];
#pragma unroll
        for (int n = 0; n < 32; ++n)
            s += be2[n] * W[(128 + n) * 128 + col];
        bp[col] = s;
    }
}

__global__ __launch_bounds__(256, 2) void egnn_edges(
    const float* __restrict__ h, const float* __restrict__ x,
    const int* __restrict__ srcg, const int* __restrict__ dstg,
    const float* __restrict__ dist,
    const float* __restrict__ We1, const float* __restrict__ be1,
    const float* __restrict__ Wn2, const float* __restrict__ bn2,
    const float* __restrict__ Wc2,
    const float* __restrict__ wsW,
    float* __restrict__ outh, float* __restrict__ outx) {

    __shared__ __align__(16) unsigned short mlds[64 * MSTRIDE];  // m_input tile bf16
    __shared__ __align__(16) unsigned short hl[64 * HSTRIDE];    // hidden tile bf16
    __shared__ int src_l[64];
    __shared__ int dst_l[64];
    __shared__ float we1_l[32], be1_l[32];
    __shared__ float part_l[256];

    const int tid  = threadIdx.x;
    const int w    = tid >> 6;        // wave 0..3
    const int lane = tid & 63;
    const int l15  = lane & 15;
    const int quad = lane >> 4;

    const float* Wn1p = wsW + WS_WN1P;
    const float* Wc1p = wsW + WS_WC1P;
    const float* bn1p = wsW + WS_BN1P;
    const float* bc1p = wsW + WS_BC1P;

    if (tid < 32) { we1_l[tid] = We1[tid]; be1_l[tid] = be1[tid]; }

    // ---- one-time: B-fragments to registers (from folded weights) ----
    // GEMM1: wave w covers hidden cols [w*32, w*32+32) via 2 N-tiles of 16.
    bf16x8 wn1f[5][2], wc1f[5][2];
#pragma unroll
    for (int kc = 0; kc < 5; ++kc) {
#pragma unroll
        for (int nt = 0; nt < 2; ++nt) {
            unsigned short un[8], uc[8];
            const int n = w * 32 + nt * 16 + l15;
#pragma unroll
            for (int j = 0; j < 8; ++j) {
                const int k = kc * 32 + quad * 8 + j;
                un[j] = f2bf(Wn1p[k * HDIM + n]);
                uc[j] = f2bf(Wc1p[k * HDIM + n]);
            }
            wn1f[kc][nt] = mk_frag(un);
            wc1f[kc][nt] = mk_frag(uc);
        }
    }
    // GEMM2 (node): wave w covers out cols [w*16, w*16+16)
    bf16x8 wn2f[4];
#pragma unroll
    for (int kc = 0; kc < 4; ++kc) {
        unsigned short u[8];
        const int n = w * 16 + l15;
#pragma unroll
        for (int j = 0; j < 8; ++j) {
            const int k = kc * 32 + quad * 8 + j;
            u[j] = f2bf(Wn2[k * NDIM + n]);
        }
        wn2f[kc] = mk_frag(u);
    }
    const float biasN0 = bn1p[w * 32 + l15];
    const float biasN1 = bn1p[w * 32 + 16 + l15];
    const float biasC0 = bc1p[w * 32 + l15];
    const float biasC1 = bc1p[w * 32 + 16 + l15];
    const float bias2v = bn2[w * 16 + l15];
    const float wcA = Wc2[w * 32 + l15];          // coord Wc2 slice, nt=0
    const float wcB = Wc2[w * 32 + 16 + l15];     // nt=1

    for (int tile = blockIdx.x; tile < NTILES; tile += gridDim.x) {
        __syncthreads();   // (1) protect LDS reuse from previous iteration

        if (tid < 64) {
            const int e = tile * 64 + tid;
            src_l[tid] = srcg[e];
            dst_l[tid] = dstg[e];
        }
        __syncthreads();   // (2)

        // ---- stage m_input = [h[src] | h[dst] | s] as bf16 ----
        {
            const int c4 = tid & 15, sub = tid >> 4;
#pragma unroll
            for (int it = 0; it < 4; ++it) {
                const int el = sub + it * 16;
                const float4 hs = *(const float4*)(h + (size_t)src_l[el] * NDIM + c4 * 4);
                const float4 hd = *(const float4*)(h + (size_t)dst_l[el] * NDIM + c4 * 4);
                ushort4v us = { f2bf(hs.x), f2bf(hs.y), f2bf(hs.z), f2bf(hs.w) };
                ushort4v ud = { f2bf(hd.x), f2bf(hd.y), f2bf(hd.z), f2bf(hd.w) };
                *(ushort4v*)&mlds[el * MSTRIDE + c4 * 4] = us;
                *(ushort4v*)&mlds[el * MSTRIDE + 64 + c4 * 4] = ud;
            }
        }
        // ---- stage s = silu(d*We1 + be1)  (8 values/thread, We2 folded away) ----
        {
            const int el = tid >> 2, j0 = (tid & 3) * 8;
            const float dv = dist[tile * 64 + el];
            ushort8 u;
#pragma unroll
            for (int j = 0; j < 8; ++j)
                u[j] = f2bf(silu(dv * we1_l[j0 + j] + be1_l[j0 + j]));
            *(ushort8*)&mlds[el * MSTRIDE + 128 + j0] = u;
        }
        __syncthreads();   // (3)

        // ---- GEMM1: [64x160] @ {Wn1', Wc1'} -> hidden [64x128] per path ----
        f32x4 accN[4][2], accC[4][2];
#pragma unroll
        for (int mt = 0; mt < 4; ++mt) {
            accN[mt][0] = (f32x4){biasN0, biasN0, biasN0, biasN0};
            accN[mt][1] = (f32x4){biasN1, biasN1, biasN1, biasN1};
            accC[mt][0] = (f32x4){biasC0, biasC0, biasC0, biasC0};
            accC[mt][1] = (f32x4){biasC1, biasC1, biasC1, biasC1};
        }
#pragma unroll
        for (int kc = 0; kc < 5; ++kc) {
            bf16x8 af[4];
#pragma unroll
            for (int mt = 0; mt < 4; ++mt)
                af[mt] = ld_frag(&mlds[(mt * 16 + l15) * MSTRIDE + kc * 32 + quad * 8]);
#pragma unroll
            for (int mt = 0; mt < 4; ++mt) {
#pragma unroll
                for (int nt = 0; nt < 2; ++nt) {
                    accN[mt][nt] = __builtin_amdgcn_mfma_f32_16x16x32_bf16(
                        af[mt], wn1f[kc][nt], accN[mt][nt], 0, 0, 0);
                    accC[mt][nt] = __builtin_amdgcn_mfma_f32_16x16x32_bf16(
                        af[mt], wc1f[kc][nt], accC[mt][nt], 0, 0, 0);
                }
            }
        }

        // ---- node path: silu -> hl (C-layout -> A-layout round trip) ----
#pragma unroll
        for (int mt = 0; mt < 4; ++mt)
#pragma unroll
            for (int nt = 0; nt < 2; ++nt)
#pragma unroll
                for (int r = 0; r < 4; ++r)
                    hl[(mt * 16 + quad * 4 + r) * HSTRIDE + w * 32 + nt * 16 + l15] =
                        f2bf(silu(accN[mt][nt][r]));

        // ---- coord path: in-register silu*Wc2 + butterfly reduce over l15 ----
        // C-frag: value (mt,nt,r) is edge row (mt*16+quad*4+r), col (w*32+nt*16+l15).
        // p[mt*4+r] = this lane's column contribution; xor-reduce over the 16
        // lanes sharing `quad` leaves lane l15 holding the full w-slice sum for
        // p-index == l15, i.e. edge (l15>>2)*16 + quad*4 + (l15&3).
        {
            float p[16];
#pragma unroll
            for (int mt = 0; mt < 4; ++mt)
#pragma unroll
                for (int r = 0; r < 4; ++r)
                    p[mt * 4 + r] = silu(accC[mt][0][r]) * wcA + silu(accC[mt][1][r]) * wcB;

            float q8[8];
#pragma unroll
            for (int i = 0; i < 8; ++i) {
                const float send = (l15 & 8) ? p[i] : p[i + 8];
                const float recv = __shfl_xor(send, 8, 64);
                q8[i] = ((l15 & 8) ? p[i + 8] : p[i]) + recv;
            }
            float q4[4];
#pragma unroll
            for (int i = 0; i < 4; ++i) {
                const float send = (l15 & 4) ? q8[i] : q8[i + 4];
                const float recv = __shfl_xor(send, 4, 64);
                q4[i] = ((l15 & 4) ? q8[i + 4] : q8[i]) + recv;
            }
            float q2[2];
#pragma unroll
            for (int i = 0; i < 2; ++i) {
                const float send = (l15 & 2) ? q4[i] : q4[i + 2];
                const float recv = __shfl_xor(send, 2, 64);
                q2[i] = ((l15 & 2) ? q4[i + 2] : q4[i]) + recv;
            }
            {
                const float send = (l15 & 1) ? q2[0] : q2[1];
                const float recv = __shfl_xor(send, 1, 64);
                const float tot = ((l15 & 1) ? q2[1] : q2[0]) + recv;
                const int edge = (l15 >> 2) * 16 + quad * 4 + (l15 & 3);
                part_l[w * 64 + edge] = tot;
            }
        }
        __syncthreads();   // (4) hl ready for GEMM2, part_l ready for epilogue

        // ---- GEMM2 node: [64x128] @ Wn2 -> m [64x64], scatter ----
        f32x4 acc2[4];
#pragma unroll
        for (int mt = 0; mt < 4; ++mt) acc2[mt] = (f32x4){bias2v, bias2v, bias2v, bias2v};
#pragma unroll
        for (int kc = 0; kc < 4; ++kc) {
#pragma unroll
            for (int mt = 0; mt < 4; ++mt) {
                bf16x8 a2 = ld_frag(&hl[(mt * 16 + l15) * HSTRIDE + kc * 32 + quad * 8]);
                acc2[mt] = __builtin_amdgcn_mfma_f32_16x16x32_bf16(a2, wn2f[kc], acc2[mt], 0, 0, 0);
            }
        }
#pragma unroll
        for (int mt = 0; mt < 4; ++mt) {
#pragma unroll
            for (int r = 0; r < 4; ++r) {
                const int el = mt * 16 + quad * 4 + r;
                atomicAdd(outh + (size_t)dst_l[el] * NDIM + w * 16 + l15, acc2[mt][r]);
            }
        }

        // ---- coord epilogue: sum 4 wave partials, scale direction, scatter ----
        if (tid < 64) {
            const float cw = part_l[tid] + part_l[64 + tid] + part_l[128 + tid] + part_l[192 + tid];
            const int sn = src_l[tid], dn = dst_l[tid];
            const float dx = x[sn * 3 + 0] - x[dn * 3 + 0];
            const float dy = x[sn * 3 + 1] - x[dn * 3 + 1];
            const float dz = x[sn * 3 + 2] - x[dn * 3 + 2];
            float len = sqrtf(dx * dx + dy * dy + dz * dz);
            len = fmaxf(len, 1e-8f);
            const float f = cw / len;
            atomicAdd(outx + (size_t)dn * 3 + 0, f * dx);
            atomicAdd(outx + (size_t)dn * 3 + 1, f * dy);
            atomicAdd(outx + (size_t)dn * 3 + 2, f * dz);
        }
    }
}

extern "C" void kernel_launch(void* const* d_in, const int* in_sizes, int n_in,
                              void* d_out, int out_size, void* d_ws, size_t ws_size,
                              hipStream_t stream) {
    const float* h    = (const float*)d_in[0];
    const float* x    = (const float*)d_in[1];
    const int*   ei   = (const int*)d_in[2];     // int32, [2, NE]
    const float* dist = (const float*)d_in[3];
    const float* We1  = (const float*)d_in[4];
    const float* be1  = (const float*)d_in[5];
    const float* We2  = (const float*)d_in[6];
    const float* be2  = (const float*)d_in[7];
    const float* Wn1  = (const float*)d_in[8];
    const float* bn1  = (const float*)d_in[9];
    const float* Wn2  = (const float*)d_in[10];
    const float* bn2  = (const float*)d_in[11];
    const float* Wc1  = (const float*)d_in[12];
    const float* bc1  = (const float*)d_in[13];
    const float* Wc2  = (const float*)d_in[14];

    float* outh = (float*)d_out;
    float* outx = outh + (size_t)NH;
    float* ws   = (float*)d_ws;

    fold_weights<<<322, 128, 0, stream>>>(We2, be2, Wn1, bn1, Wc1, bc1, ws);
    init_out<<<(NH + NX + 255) / 256, 256, 0, stream>>>(h, x, (float*)d_out);
    egnn_edges<<<512, 256, 0, stream>>>(h, x, ei, ei + NE, dist,
                                        We1, be1, Wn2, bn2, Wc2, ws,
                                        outh, outx);
}

// Round 2
// 425.772 us; speedup vs baseline: 1.0482x; 1.0482x over previous
//
#include <hip/hip_runtime.h>

// EGNN fused layer, MI355X gfx950 — v3 (latency/occupancy round).
// out[0 : 50000*64)          = h + segment_sum(node messages, dst)
// out[50000*64 : +50000*3)   = x + segment_sum(coord updates, dst)
//
// v2 post-mortem: VALU cut landed (VALUBusy 57->36%) but dur flat ->
// latency-bound, not VALU-bound. All pipes low, occupancy 22%.
// Changes vs v2:
//  - grid 512 -> 1024: occupancy was grid-capped at 2 blocks/CU; LDS
//    (40960 B x 4 = exactly 160 KiB) and VGPR (128 -> 4 waves/SIMD) allow 4.
//  - lgkm-only barriers: __syncthreads() drains vmcnt(0), forcing all
//    ~19 scattered atomics/tile to retire at every barrier (4/tile).
//    All cross-thread deps here flow through LDS -> s_waitcnt lgkmcnt(0)
//    + raw s_barrier suffices; atomics stay in flight across tiles (T4).
//  - src/dst prefetched into regs before barrier (1).

#define NN 50000
#define NE 800000
#define NDIM 64
#define HDIM 128
#define EDIM 32
#define NTILES (NE / 64)      // 12500, exact
#define MSTRIDE 168           // m_input LDS row stride (ushorts): 160 + 8 pad
#define HSTRIDE 136           // hidden LDS row stride: 128 + 8 pad
#define NH (NN * NDIM)        // 3,200,000
#define NX (NN * 3)           // 150,000

// workspace layout (floats)
#define WS_WN1P 0             // [160][128]
#define WS_WC1P 20480         // [160][128]
#define WS_BN1P 40960         // [128]
#define WS_BC1P 41088         // [128]

typedef __bf16 bf16x8 __attribute__((ext_vector_type(8)));
typedef float f32x4 __attribute__((ext_vector_type(4)));
typedef unsigned short ushort8 __attribute__((ext_vector_type(8)));
typedef unsigned short ushort4v __attribute__((ext_vector_type(4)));

__device__ __forceinline__ unsigned short f2bf(float f) {
    union { __bf16 b; unsigned short u; } c;
    c.b = (__bf16)f;            // HW v_cvt (RNE)
    return c.u;
}
__device__ __forceinline__ float silu(float v) {
    return __fdividef(v, 1.0f + __expf(-v));
}

// lgkm-only barrier: all cross-thread deps in this kernel are through LDS.
// Deliberately does NOT drain vmcnt -> scattered atomics stay in flight.
__device__ __forceinline__ void bar_lds() {
    asm volatile("s_waitcnt lgkmcnt(0)" ::: "memory");
    __builtin_amdgcn_s_barrier();
}

__device__ __forceinline__ bf16x8 ld_frag(const unsigned short* p) {
    union { ushort8 u; bf16x8 v; } c;
    c.u = *(const ushort8*)p;
    return c.v;
}
__device__ __forceinline__ bf16x8 mk_frag(const unsigned short* u) {
    union { ushort8 uu; bf16x8 v; } c;
#pragma unroll
    for (int j = 0; j < 8; ++j) c.uu[j] = u[j];
    return c.v;
}

__global__ void init_out(const float* __restrict__ h, const float* __restrict__ x,
                         float* __restrict__ out) {
    int i = blockIdx.x * 256 + threadIdx.x;
    if (i < NH) out[i] = h[i];
    else if (i < NH + NX) out[i] = x[i - NH];
}

// Fold We2/be2 into the 160->128 GEMM weights.  Grid: 322 blocks x 128 thr.
__global__ __launch_bounds__(128) void fold_weights(
    const float* __restrict__ We2, const float* __restrict__ be2,
    const float* __restrict__ Wn1, const float* __restrict__ bn1,
    const float* __restrict__ Wc1, const float* __restrict__ bc1,
    float* __restrict__ ws) {
    const int b = blockIdx.x;
    const int col = threadIdx.x;
    if (b < 320) {
        const int path = (b >= 160);
        const float* W = path ? Wc1 : Wn1;
        float* Wp = ws + (path ? WS_WC1P : WS_WN1P);
        const int r = path ? (b - 160) : b;
        if (r < 128) {
            Wp[r * 128 + col] = W[r * 128 + col];
        } else {
            const int j = r - 128;          // s-dim index 0..31
            float s = 0.0f;
#pragma unroll
            for (int n = 0; n < 32; ++n)
                s += We2[j * 32 + n] * W[(128 + n) * 128 + col];
            Wp[r * 128 + col] = s;
        }
    } else {
        const int path = b - 320;
        const float* W = path ? Wc1 : Wn1;
        const float* bb = path ? bc1 : bn1;
        float* bp = ws + (path ? WS_BC1P : WS_BN1P);
        float s = bb[col];
#pragma unroll
        for (int n = 0; n < 32; ++n)
            s += be2[n] * W[(128 + n) * 128 + col];
        bp[col] = s;
    }
}

__global__ __launch_bounds__(256, 2) void egnn_edges(
    const float* __restrict__ h, const float* __restrict__ x,
    const int* __restrict__ srcg, const int* __restrict__ dstg,
    const float* __restrict__ dist,
    const float* __restrict__ We1, const float* __restrict__ be1,
    const float* __restrict__ Wn2, const float* __restrict__ bn2,
    const float* __restrict__ Wc2,
    const float* __restrict__ wsW,
    float* __restrict__ outh, float* __restrict__ outx) {

    __shared__ __align__(16) unsigned short mlds[64 * MSTRIDE];  // m_input tile bf16
    __shared__ __align__(16) unsigned short hl[64 * HSTRIDE];    // hidden tile bf16
    __shared__ int src_l[64];
    __shared__ int dst_l[64];
    __shared__ float we1_l[32], be1_l[32];
    __shared__ float part_l[256];

    const int tid  = threadIdx.x;
    const int w    = tid >> 6;        // wave 0..3
    const int lane = tid & 63;
    const int l15  = lane & 15;
    const int quad = lane >> 4;

    const float* Wn1p = wsW + WS_WN1P;
    const float* Wc1p = wsW + WS_WC1P;
    const float* bn1p = wsW + WS_BN1P;
    const float* bc1p = wsW + WS_BC1P;

    if (tid < 32) { we1_l[tid] = We1[tid]; be1_l[tid] = be1[tid]; }

    // ---- one-time: B-fragments to registers (from folded weights) ----
    bf16x8 wn1f[5][2], wc1f[5][2];
#pragma unroll
    for (int kc = 0; kc < 5; ++kc) {
#pragma unroll
        for (int nt = 0; nt < 2; ++nt) {
            unsigned short un[8], uc[8];
            const int n = w * 32 + nt * 16 + l15;
#pragma unroll
            for (int j = 0; j < 8; ++j) {
                const int k = kc * 32 + quad * 8 + j;
                un[j] = f2bf(Wn1p[k * HDIM + n]);
                uc[j] = f2bf(Wc1p[k * HDIM + n]);
            }
            wn1f[kc][nt] = mk_frag(un);
            wc1f[kc][nt] = mk_frag(uc);
        }
    }
    bf16x8 wn2f[4];
#pragma unroll
    for (int kc = 0; kc < 4; ++kc) {
        unsigned short u[8];
        const int n = w * 16 + l15;
#pragma unroll
        for (int j = 0; j < 8; ++j) {
            const int k = kc * 32 + quad * 8 + j;
            u[j] = f2bf(Wn2[k * NDIM + n]);
        }
        wn2f[kc] = mk_frag(u);
    }
    const float biasN0 = bn1p[w * 32 + l15];
    const float biasN1 = bn1p[w * 32 + 16 + l15];
    const float biasC0 = bc1p[w * 32 + l15];
    const float biasC1 = bc1p[w * 32 + 16 + l15];
    const float bias2v = bn2[w * 16 + l15];
    const float wcA = Wc2[w * 32 + l15];          // coord Wc2 slice, nt=0
    const float wcB = Wc2[w * 32 + 16 + l15];     // nt=1

    for (int tile = blockIdx.x; tile < NTILES; tile += gridDim.x) {
        // prefetch src/dst into regs while previous tile's epilogue finishes
        int pf_s = 0, pf_d = 0;
        if (tid < 64) {
            const int e = tile * 64 + tid;
            pf_s = srcg[e];
            pf_d = dstg[e];
        }
        bar_lds();   // (1) protect LDS reuse from previous iteration

        if (tid < 64) { src_l[tid] = pf_s; dst_l[tid] = pf_d; }
        bar_lds();   // (2)

        // ---- stage m_input = [h[src] | h[dst] | s] as bf16 ----
        {
            const int c4 = tid & 15, sub = tid >> 4;
#pragma unroll
            for (int it = 0; it < 4; ++it) {
                const int el = sub + it * 16;
                const float4 hs = *(const float4*)(h + (size_t)src_l[el] * NDIM + c4 * 4);
                const float4 hd = *(const float4*)(h + (size_t)dst_l[el] * NDIM + c4 * 4);
                ushort4v us = { f2bf(hs.x), f2bf(hs.y), f2bf(hs.z), f2bf(hs.w) };
                ushort4v ud = { f2bf(hd.x), f2bf(hd.y), f2bf(hd.z), f2bf(hd.w) };
                *(ushort4v*)&mlds[el * MSTRIDE + c4 * 4] = us;
                *(ushort4v*)&mlds[el * MSTRIDE + 64 + c4 * 4] = ud;
            }
        }
        // ---- stage s = silu(d*We1 + be1)  (8 values/thread) ----
        {
            const int el = tid >> 2, j0 = (tid & 3) * 8;
            const float dv = dist[tile * 64 + el];
            ushort8 u;
#pragma unroll
            for (int j = 0; j < 8; ++j)
                u[j] = f2bf(silu(dv * we1_l[j0 + j] + be1_l[j0 + j]));
            *(ushort8*)&mlds[el * MSTRIDE + 128 + j0] = u;
        }
        bar_lds();   // (3)

        // ---- GEMM1: [64x160] @ {Wn1', Wc1'} -> hidden [64x128] per path ----
        f32x4 accN[4][2], accC[4][2];
#pragma unroll
        for (int mt = 0; mt < 4; ++mt) {
            accN[mt][0] = (f32x4){biasN0, biasN0, biasN0, biasN0};
            accN[mt][1] = (f32x4){biasN1, biasN1, biasN1, biasN1};
            accC[mt][0] = (f32x4){biasC0, biasC0, biasC0, biasC0};
            accC[mt][1] = (f32x4){biasC1, biasC1, biasC1, biasC1};
        }
#pragma unroll
        for (int kc = 0; kc < 5; ++kc) {
            bf16x8 af[4];
#pragma unroll
            for (int mt = 0; mt < 4; ++mt)
                af[mt] = ld_frag(&mlds[(mt * 16 + l15) * MSTRIDE + kc * 32 + quad * 8]);
#pragma unroll
            for (int mt = 0; mt < 4; ++mt) {
#pragma unroll
                for (int nt = 0; nt < 2; ++nt) {
                    accN[mt][nt] = __builtin_amdgcn_mfma_f32_16x16x32_bf16(
                        af[mt], wn1f[kc][nt], accN[mt][nt], 0, 0, 0);
                    accC[mt][nt] = __builtin_amdgcn_mfma_f32_16x16x32_bf16(
                        af[mt], wc1f[kc][nt], accC[mt][nt], 0, 0, 0);
                }
            }
        }

        // ---- node path: silu -> hl (C-layout -> A-layout round trip) ----
#pragma unroll
        for (int mt = 0; mt < 4; ++mt)
#pragma unroll
            for (int nt = 0; nt < 2; ++nt)
#pragma unroll
                for (int r = 0; r < 4; ++r)
                    hl[(mt * 16 + quad * 4 + r) * HSTRIDE + w * 32 + nt * 16 + l15] =
                        f2bf(silu(accN[mt][nt][r]));

        // ---- coord path: in-register silu*Wc2 + butterfly reduce over l15 ----
        {
            float p[16];
#pragma unroll
            for (int mt = 0; mt < 4; ++mt)
#pragma unroll
                for (int r = 0; r < 4; ++r)
                    p[mt * 4 + r] = silu(accC[mt][0][r]) * wcA + silu(accC[mt][1][r]) * wcB;

            float q8[8];
#pragma unroll
            for (int i = 0; i < 8; ++i) {
                const float send = (l15 & 8) ? p[i] : p[i + 8];
                const float recv = __shfl_xor(send, 8, 64);
                q8[i] = ((l15 & 8) ? p[i + 8] : p[i]) + recv;
            }
            float q4[4];
#pragma unroll
            for (int i = 0; i < 4; ++i) {
                const float send = (l15 & 4) ? q8[i] : q8[i + 4];
                const float recv = __shfl_xor(send, 4, 64);
                q4[i] = ((l15 & 4) ? q8[i + 4] : q8[i]) + recv;
            }
            float q2[2];
#pragma unroll
            for (int i = 0; i < 2; ++i) {
                const float send = (l15 & 2) ? q4[i] : q4[i + 2];
                const float recv = __shfl_xor(send, 2, 64);
                q2[i] = ((l15 & 2) ? q4[i + 2] : q4[i]) + recv;
            }
            {
                const float send = (l15 & 1) ? q2[0] : q2[1];
                const float recv = __shfl_xor(send, 1, 64);
                const float tot = ((l15 & 1) ? q2[1] : q2[0]) + recv;
                const int edge = (l15 >> 2) * 16 + quad * 4 + (l15 & 3);
                part_l[w * 64 + edge] = tot;
            }
        }
        bar_lds();   // (4) hl ready for GEMM2, part_l ready for epilogue

        // ---- GEMM2 node: [64x128] @ Wn2 -> m [64x64], scatter ----
        f32x4 acc2[4];
#pragma unroll
        for (int mt = 0; mt < 4; ++mt) acc2[mt] = (f32x4){bias2v, bias2v, bias2v, bias2v};
#pragma unroll
        for (int kc = 0; kc < 4; ++kc) {
#pragma unroll
            for (int mt = 0; mt < 4; ++mt) {
                bf16x8 a2 = ld_frag(&hl[(mt * 16 + l15) * HSTRIDE + kc * 32 + quad * 8]);
                acc2[mt] = __builtin_amdgcn_mfma_f32_16x16x32_bf16(a2, wn2f[kc], acc2[mt], 0, 0, 0);
            }
        }
#pragma unroll
        for (int mt = 0; mt < 4; ++mt) {
#pragma unroll
            for (int r = 0; r < 4; ++r) {
                const int el = mt * 16 + quad * 4 + r;
                atomicAdd(outh + (size_t)dst_l[el] * NDIM + w * 16 + l15, acc2[mt][r]);
            }
        }

        // ---- coord epilogue: sum 4 wave partials, scale direction, scatter ----
        if (tid < 64) {
            const float cw = part_l[tid] + part_l[64 + tid] + part_l[128 + tid] + part_l[192 + tid];
            const int sn = src_l[tid], dn = dst_l[tid];
            const float dx = x[sn * 3 + 0] - x[dn * 3 + 0];
            const float dy = x[sn * 3 + 1] - x[dn * 3 + 1];
            const float dz = x[sn * 3 + 2] - x[dn * 3 + 2];
            float len = sqrtf(dx * dx + dy * dy + dz * dz);
            len = fmaxf(len, 1e-8f);
            const float f = cw / len;
            atomicAdd(outx + (size_t)dn * 3 + 0, f * dx);
            atomicAdd(outx + (size_t)dn * 3 + 1, f * dy);
            atomicAdd(outx + (size_t)dn * 3 + 2, f * dz);
        }
    }
}

extern "C" void kernel_launch(void* const* d_in, const int* in_sizes, int n_in,
                              void* d_out, int out_size, void* d_ws, size_t ws_size,
                              hipStream_t stream) {
    const float* h    = (const float*)d_in[0];
    const float* x    = (const float*)d_in[1];
    const int*   ei   = (const int*)d_in[2];     // int32, [2, NE]
    const float* dist = (const float*)d_in[3];
    const float* We1  = (const float*)d_in[4];
    const float* be1  = (const float*)d_in[5];
    const float* We2  = (const float*)d_in[6];
    const float* be2  = (const float*)d_in[7];
    const float* Wn1  = (const float*)d_in[8];
    const float* bn1  = (const float*)d_in[9];
    const float* Wn2  = (const float*)d_in[10];
    const float* bn2  = (const float*)d_in[11];
    const float* Wc1  = (const float*)d_in[12];
    const float* bc1  = (const float*)d_in[13];
    const float* Wc2  = (const float*)d_in[14];

    float* outh = (float*)d_out;
    float* outx = outh + (size_t)NH;
    float* ws   = (float*)d_ws;

    fold_weights<<<322, 128, 0, stream>>>(We2, be2, Wn1, bn1, Wc1, bc1, ws);
    init_out<<<(NH + NX + 255) / 256, 256, 0, stream>>>(h, x, (float*)d_out);
    // grid 1024: 4 blocks/CU (LDS 40960*4 = 160 KiB exactly, VGPR 128 -> 4 waves/SIMD)
    egnn_edges<<<1024, 256, 0, stream>>>(h, x, ei, ei + NE, dist,
                                         We1, be1, Wn2, bn2, Wc2, ws,
                                         outh, outx);
}